// Round 8
// baseline (353.419 us; speedup 1.0000x reference)
//
#include <hip/hip_runtime.h>
#include <math.h>

#define S_ROWS 2047
#define DIM 256
#define HID 512
#define NHEADS 8
#define DH 32
#define NBINS 16
#define AFF_OUT 49

typedef short bf16x8 __attribute__((ext_vector_type(8)));
typedef float f32x4 __attribute__((ext_vector_type(4)));
typedef float f32x16 __attribute__((ext_vector_type(16)));
typedef unsigned short u16x8 __attribute__((ext_vector_type(8)));
typedef unsigned short u16x4 __attribute__((ext_vector_type(4)));

__device__ inline unsigned short f2b(float f) {
    unsigned int u = __float_as_uint(f);
    u += 0x7FFFu + ((u >> 16) & 1u);      // round-to-nearest-even
    return (unsigned short)(u >> 16);
}

// ---------------------------------------------------------------------------
// Fused setup (verified): weight f32->bf16 conversion (+ew0 zero-pad to K=64),
// circular-feature embedding, pos copy + out[6144]=0.
// ---------------------------------------------------------------------------
#define W_MAIN 3957248
#define EW0P_N 32768
#define P0 (W_MAIN / 4)
#define P1 (P0 + EW0P_N / 4)
#define P2 (P1 + 2048 * 64 / 4)
#define P3 (P2 + 1537)
__global__ __launch_bounds__(256) void setup_kernel(
    const float* __restrict__ pos, const float* __restrict__ scale,
    const float* __restrict__ press, const float* __restrict__ temp,
    const float* __restrict__ e_w0, const float* __restrict__ p0,
    const float* __restrict__ p1, const float* __restrict__ p2,
    const float* __restrict__ p3, const float* __restrict__ p4,
    const float* __restrict__ p5, const float* __restrict__ p6,
    const float* __restrict__ p7, const float* __restrict__ p8,
    const float* __restrict__ p9, const float* __restrict__ p10,
    const float* __restrict__ p11, unsigned short* __restrict__ dst,
    unsigned short* __restrict__ cond, float* __restrict__ out)
{
    const int offs[13] = {0, 262144, 393216, 655360, 917504, 1179648, 1441792,
                          1966080, 3014656, 3538944, 3670016, 3932160, 3957248};
    const float* srcs[12] = {p0,p1,p2,p3,p4,p5,p6,p7,p8,p9,p10,p11};
    for (int i4 = blockIdx.x * blockDim.x + threadIdx.x; i4 < P3;
         i4 += gridDim.x * blockDim.x) {
        if (i4 < P0) {
            int e = i4 * 4;
            int s = 0;
            #pragma unroll
            for (int j = 1; j < 12; j++) s += (e >= offs[j]);
            const float4 v = *(const float4*)(srcs[s] + (e - offs[s]));
            u16x4 o;
            o[0] = f2b(v.x); o[1] = f2b(v.y); o[2] = f2b(v.z); o[3] = f2b(v.w);
            *(u16x4*)(dst + EW0P_N + e) = o;
        } else if (i4 < P1) {
            int e = (i4 - P0) * 4;
            u16x4 o;
            #pragma unroll
            for (int r = 0; r < 4; r++) {
                int ee = e + r;
                int row = ee >> 6, col = ee & 63;
                o[r] = (col < 35) ? f2b(e_w0[row * 35 + col]) : (unsigned short)0;
            }
            *(u16x4*)(dst + e) = o;
        } else if (i4 < P2) {
            int e = (i4 - P1) * 4;
            int row = e >> 6;
            u16x4 o;
            #pragma unroll
            for (int r = 0; r < 4; r++) {
                int c = (e + r) & 63;
                float v = 0.f;
                if (row < S_ROWS) {
                    if (c < 32) {
                        int coord = c >> 4;
                        int w = c & 15;
                        float x = pos[(row + 1) * 3 + coord];
                        float f = 6.283185307179586f * (float)((w & 7) + 1);
                        float ang = x * f;
                        v = (w < 8) ? cosf(ang) : sinf(ang);
                    } else if (c == 32) v = scale[0];
                    else if (c == 33) v = temp[0];
                    else if (c == 34) v = press[0];
                }
                o[r] = f2b(v);
            }
            *(u16x4*)(cond + e) = o;
        } else {
            int e = (i4 - P2) * 4;
            #pragma unroll
            for (int r = 0; r < 4; r++) {
                int ee = e + r;
                if (ee < 6144) out[ee] = pos[ee];
                else if (ee == 6144) out[ee] = 0.f;
            }
        }
    }
}

// ---------------------------------------------------------------------------
// bf16 MFMA GEMM, 32x32 tile, KSTEP=64 (verified; used for K=64 only).
// ---------------------------------------------------------------------------
#define LDK 72
__global__ __launch_bounds__(256, 4) void gemm_bf16_64(
    const unsigned short* __restrict__ Ab, const unsigned short* __restrict__ W,
    const float* __restrict__ bias, const float* resF,
    float* Cf, unsigned short* Cb, int M, int K, int relu)
{
    __shared__ unsigned short As[32][LDK];
    __shared__ unsigned short Bs[32][LDK];
    int tid = threadIdx.x;
    int wave = tid >> 6, lane = tid & 63;
    int quad = lane >> 4, l16 = lane & 15;
    int rowf = (wave & 1) << 4, colf = (wave >> 1) << 4;
    int row0 = blockIdx.y << 5, col0 = blockIdx.x << 5;
    int srow = tid >> 3, scol = (tid & 7) << 3;

    f32x4 acc = {0.f, 0.f, 0.f, 0.f};

    const u16x8* ap = (const u16x8*)(Ab + (size_t)(row0 + srow) * K + scol);
    const u16x8* wp = (const u16x8*)(W + (size_t)(col0 + srow) * K + scol);
    u16x8 a0 = ap[0];
    u16x8 b0 = wp[0];

    for (int k0 = 0; k0 < K; k0 += 64) {
        *(u16x8*)&As[srow][scol] = a0;
        *(u16x8*)&Bs[srow][scol] = b0;
        __syncthreads();
        if (k0 + 64 < K) {
            ap += 8; wp += 8;
            a0 = ap[0]; b0 = wp[0];
        }
        #pragma unroll
        for (int kt = 0; kt < 64; kt += 32) {
            bf16x8 af = *(bf16x8*)&As[rowf + l16][kt + (quad << 3)];
            bf16x8 bf = *(bf16x8*)&Bs[colf + l16][kt + (quad << 3)];
            acc = __builtin_amdgcn_mfma_f32_16x16x32_bf16(af, bf, acc, 0, 0, 0);
        }
        __syncthreads();
    }
    int col = col0 + colf + l16;
    if (col < M) {
        float bv = bias ? bias[col] : 0.f;
        #pragma unroll
        for (int r = 0; r < 4; r++) {
            int row = row0 + rowf + (quad << 2) + r;
            if (row >= S_ROWS) continue;
            float v = acc[r] + bv;
            if (resF) v += resF[(size_t)row * M + col];
            if (relu) v = fmaxf(v, 0.f);
            if (Cf) Cf[(size_t)row * M + col] = v;
            if (Cb) Cb[(size_t)row * M + col] = f2b(v);
        }
    }
}

// ---------------------------------------------------------------------------
// bf16 MFMA GEMM, 32x32 tile, KSTEP=128 (verified round 7). K % 128 == 0.
// ---------------------------------------------------------------------------
#define LDW 136
__global__ __launch_bounds__(256, 4) void gemm_bf16_128(
    const unsigned short* __restrict__ Ab, const unsigned short* __restrict__ W,
    const float* __restrict__ bias, const float* resF,
    float* Cf, unsigned short* Cb, int M, int K, int relu)
{
    __shared__ unsigned short As[32][LDW];
    __shared__ unsigned short Bs[32][LDW];
    int tid = threadIdx.x;
    int wave = tid >> 6, lane = tid & 63;
    int quad = lane >> 4, l16 = lane & 15;
    int rowf = (wave & 1) << 4, colf = (wave >> 1) << 4;
    int row0 = blockIdx.y << 5, col0 = blockIdx.x << 5;
    int srow = tid >> 3, scol = (tid & 7) << 4;

    f32x4 acc = {0.f, 0.f, 0.f, 0.f};

    const u16x8* ap = (const u16x8*)(Ab + (size_t)(row0 + srow) * K + scol);
    const u16x8* wp = (const u16x8*)(W + (size_t)(col0 + srow) * K + scol);
    u16x8 a0 = ap[0], a1 = ap[1];
    u16x8 b0 = wp[0], b1 = wp[1];

    for (int k0 = 0; k0 < K; k0 += 128) {
        *(u16x8*)&As[srow][scol]     = a0;
        *(u16x8*)&As[srow][scol + 8] = a1;
        *(u16x8*)&Bs[srow][scol]     = b0;
        *(u16x8*)&Bs[srow][scol + 8] = b1;
        __syncthreads();
        if (k0 + 128 < K) {
            ap += 16; wp += 16;
            a0 = ap[0]; a1 = ap[1];
            b0 = wp[0]; b1 = wp[1];
        }
        #pragma unroll
        for (int kt = 0; kt < 128; kt += 32) {
            bf16x8 af = *(bf16x8*)&As[rowf + l16][kt + (quad << 3)];
            bf16x8 bf = *(bf16x8*)&Bs[colf + l16][kt + (quad << 3)];
            acc = __builtin_amdgcn_mfma_f32_16x16x32_bf16(af, bf, acc, 0, 0, 0);
        }
        __syncthreads();
    }
    int col = col0 + colf + l16;
    if (col < M) {
        float bv = bias ? bias[col] : 0.f;
        #pragma unroll
        for (int r = 0; r < 4; r++) {
            int row = row0 + rowf + (quad << 2) + r;
            if (row >= S_ROWS) continue;
            float v = acc[r] + bv;
            if (resF) v += resF[(size_t)row * M + col];
            if (relu) v = fmaxf(v, 0.f);
            if (Cf) Cf[(size_t)row * M + col] = v;
            if (Cb) Cb[(size_t)row * M + col] = f2b(v);
        }
    }
}

// ---------------------------------------------------------------------------
// Fused QKV GEMM (32x32 tile, KSTEP=128, K=256) -> attention-native layouts
// (verified). Grid (24, 64) = 1536 blocks.
// ---------------------------------------------------------------------------
__global__ __launch_bounds__(256, 4) void gemm_qkv(
    const unsigned short* __restrict__ Ab, const unsigned short* __restrict__ Wq,
    const unsigned short* __restrict__ Wk, const unsigned short* __restrict__ Wv,
    const float* __restrict__ bk,
    unsigned short* __restrict__ qbh, unsigned short* __restrict__ kbh,
    unsigned short* __restrict__ vbT)
{
    __shared__ unsigned short As[32][LDW];
    __shared__ unsigned short Bs[32][LDW];
    const int N = S_ROWS, K = 256;
    int tid = threadIdx.x;
    int wave = tid >> 6, lane = tid & 63;
    int quad = lane >> 4, l16 = lane & 15;
    int rowf = (wave & 1) << 4, colf = (wave >> 1) << 4;
    int row0 = blockIdx.y << 5, col0 = blockIdx.x << 5;
    int mode = col0 >> 8;                 // 0=q 1=k 2=v
    int wcol0 = col0 & 255;
    const unsigned short* W = (mode == 0) ? Wq : (mode == 1) ? Wk : Wv;
    int srow = tid >> 3, scol = (tid & 7) << 4;

    f32x4 acc = {0.f, 0.f, 0.f, 0.f};

    const u16x8* ap = (const u16x8*)(Ab + (size_t)(row0 + srow) * K + scol);
    const u16x8* wp = (const u16x8*)(W + (size_t)(wcol0 + srow) * K + scol);
    u16x8 a0 = ap[0], a1 = ap[1];
    u16x8 b0 = wp[0], b1 = wp[1];

    for (int k0 = 0; k0 < K; k0 += 128) {
        *(u16x8*)&As[srow][scol]     = a0;
        *(u16x8*)&As[srow][scol + 8] = a1;
        *(u16x8*)&Bs[srow][scol]     = b0;
        *(u16x8*)&Bs[srow][scol + 8] = b1;
        __syncthreads();
        if (k0 + 128 < K) {
            ap += 16; wp += 16;
            a0 = ap[0]; a1 = ap[1];
            b0 = wp[0]; b1 = wp[1];
        }
        #pragma unroll
        for (int kt = 0; kt < 128; kt += 32) {
            bf16x8 af = *(bf16x8*)&As[rowf + l16][kt + (quad << 3)];
            bf16x8 bf = *(bf16x8*)&Bs[colf + l16][kt + (quad << 3)];
            acc = __builtin_amdgcn_mfma_f32_16x16x32_bf16(af, bf, acc, 0, 0, 0);
        }
        __syncthreads();
    }
    int colr = wcol0 + colf + l16;        // 0..255
    int hh = colr >> 5, d = colr & 31;
    int rbase = row0 + rowf + (quad << 2);
    if (mode == 2) {
        unsigned short* dst = vbT + ((size_t)hh * 32 + d) * 2048 + rbase;
        if (rbase + 3 < N) {
            u16x4 o;
            #pragma unroll
            for (int r = 0; r < 4; r++) o[r] = f2b(acc[r]);
            *(u16x4*)dst = o;
        } else {
            #pragma unroll
            for (int r = 0; r < 4; r++)
                if (rbase + r < N) dst[r] = f2b(acc[r]);
        }
    } else {
        float bias = (mode == 1) ? bk[colr] : 0.f;
        unsigned short* dst = ((mode == 0) ? qbh : kbh) + (size_t)hh * 2048 * 32 + d;
        #pragma unroll
        for (int r = 0; r < 4; r++) {
            int row = rbase + r;
            if (row < N) {
                float v = acc[r] + bias;
                if (mode == 0) v *= 0.25506362f;
                dst[(size_t)row * 32] = f2b(v);
            }
        }
    }
}

// ---------------------------------------------------------------------------
// MFMA flash attention, 8-wave split-K-8 (verified round 7).
// Grid (64, 8) = 512 blocks x 512 threads.
// ---------------------------------------------------------------------------
__global__ __launch_bounds__(512, 2) void attn_mfma(
    const unsigned short* __restrict__ qbh,
    const unsigned short* __restrict__ kbh,
    const unsigned short* __restrict__ vbT,
    unsigned short* __restrict__ obb)
{
    int tid = threadIdx.x;
    int w = tid >> 6;                     // wave = K-chunk (0..7)
    int lane = tid & 63;
    int l31 = lane & 31, hf = lane >> 5;
    int q0 = blockIdx.x << 5;
    int h = blockIdx.y;
    int kstart = w * 256;
    int kend = min(kstart + 256, S_ROWS);

    const unsigned short* qp = qbh + ((size_t)h * 2048 + (q0 + l31)) * 32 + hf * 8;
    bf16x8 qf0 = *(const bf16x8*)(qp);
    bf16x8 qf1 = *(const bf16x8*)(qp + 16);

    const unsigned short* kb_h = kbh + (size_t)h * 2048 * 32;
    const unsigned short* vb_h = vbT + ((size_t)h * 32 + l31) * 2048;

    f32x16 acc = {};
    float m = -1e30f, l = 0.f;

    for (int key0 = kstart; key0 < kend; key0 += 32) {
        const unsigned short* kp = kb_h + (size_t)(key0 + l31) * 32 + hf * 8;
        bf16x8 kf0 = *(const bf16x8*)(kp);
        bf16x8 kf1 = *(const bf16x8*)(kp + 16);
        bf16x8 vf0 = *(const bf16x8*)(vb_h + key0 + hf * 8);
        bf16x8 vf1 = *(const bf16x8*)(vb_h + key0 + 16 + hf * 8);

        f32x16 sc = {};
        sc = __builtin_amdgcn_mfma_f32_32x32x16_bf16(kf0, qf0, sc, 0, 0, 0);
        sc = __builtin_amdgcn_mfma_f32_32x32x16_bf16(kf1, qf1, sc, 0, 0, 0);

        if (key0 + 32 > kend) {
            #pragma unroll
            for (int r = 0; r < 16; r++) {
                int kr = key0 + (r & 3) + 8 * (r >> 2) + 4 * hf;
                if (kr >= kend) sc[r] = -1e30f;
            }
        }
        float tmax = sc[0];
        #pragma unroll
        for (int r = 1; r < 16; r++) tmax = fmaxf(tmax, sc[r]);
        tmax = fmaxf(tmax, __shfl_xor(tmax, 32, 64));
        float mnew = fmaxf(m, tmax);
        float corr = __builtin_amdgcn_exp2f(m - mnew);
        m = mnew;
        float p[16];
        float ls = 0.f;
        #pragma unroll
        for (int r = 0; r < 16; r++) {
            p[r] = __builtin_amdgcn_exp2f(sc[r] - mnew);
            ls += p[r];
        }
        ls += __shfl_xor(ls, 32, 64);
        l = l * corr + ls;
        if (__ballot(corr != 1.0f)) {
            #pragma unroll
            for (int r = 0; r < 16; r++) acc[r] *= corr;
        }
        unsigned int pk[8];
        #pragma unroll
        for (int i = 0; i < 8; i++)
            pk[i] = __builtin_amdgcn_perm(__float_as_uint(p[2*i+1]),
                                          __float_as_uint(p[2*i]), 0x07060302u);
        unsigned int x[8];
        #pragma unroll
        for (int i = 0; i < 8; i++)
            x[i] = (unsigned int)__shfl_xor((int)pk[i], 32, 64);
        union { unsigned int u[4]; bf16x8 v; } B1, B2;
        B1.u[0] = hf ? x[2]  : pk[0];
        B1.u[1] = hf ? x[3]  : pk[1];
        B1.u[2] = hf ? pk[2] : x[0];
        B1.u[3] = hf ? pk[3] : x[1];
        B2.u[0] = hf ? x[6]  : pk[4];
        B2.u[1] = hf ? x[7]  : pk[5];
        B2.u[2] = hf ? pk[6] : x[4];
        B2.u[3] = hf ? pk[7] : x[5];
        acc = __builtin_amdgcn_mfma_f32_32x32x16_bf16(vf0, B1.v, acc, 0, 0, 0);
        acc = __builtin_amdgcn_mfma_f32_32x32x16_bf16(vf1, B2.v, acc, 0, 0, 0);
    }

    // ---- in-block split-K-8 combine through LDS ----
    __shared__ float sm_m[8][32];
    __shared__ float sm_l[8][32];
    __shared__ float sm_acc[8][32][36];
    if (!hf) { sm_m[w][l31] = m; sm_l[w][l31] = l; }
    #pragma unroll
    for (int g = 0; g < 4; g++) {
        float4 o4;
        o4.x = acc[4*g]; o4.y = acc[4*g+1]; o4.z = acc[4*g+2]; o4.w = acc[4*g+3];
        *(float4*)&sm_acc[w][l31][8*g + 4*hf] = o4;
    }
    __syncthreads();

    if (tid < 256) {
        int q = tid & 31;
        int dg = tid >> 5;                // 0..7
        float mmax = -1e30f;
        #pragma unroll
        for (int c = 0; c < 8; c++) mmax = fmaxf(mmax, sm_m[c][q]);
        float lsum = 0.f;
        float num0 = 0.f, num1 = 0.f, num2 = 0.f, num3 = 0.f;
        #pragma unroll
        for (int c = 0; c < 8; c++) {
            float wgt = __builtin_amdgcn_exp2f(sm_m[c][q] - mmax);
            lsum += sm_l[c][q] * wgt;
            float4 o4 = *(const float4*)&sm_acc[c][q][dg * 4];
            num0 = fmaf(o4.x, wgt, num0);
            num1 = fmaf(o4.y, wgt, num1);
            num2 = fmaf(o4.z, wgt, num2);
            num3 = fmaf(o4.w, wgt, num3);
        }
        float inv = 1.f / lsum;
        if (q0 + q < S_ROWS) {
            u16x4 st;
            st[0] = f2b(num0 * inv); st[1] = f2b(num1 * inv);
            st[2] = f2b(num2 * inv); st[3] = f2b(num3 * inv);
            *(u16x4*)(obb + (size_t)(q0 + q) * DIM + h * DH + dg * 4) = st;
        }
    }
}

// ---------------------------------------------------------------------------
// RQS spline for one row (verified math, device function).
// ---------------------------------------------------------------------------
__device__ __forceinline__ float spline_row(const float* p, float x, float* yout)
{
    float xc = fminf(fmaxf(x, 0.f), 1.f);
    float mw = -1e30f, mh = -1e30f;
    #pragma unroll
    for (int j = 0; j < NBINS; j++) {
        mw = fmaxf(mw, p[j]);
        mh = fmaxf(mh, p[NBINS + j]);
    }
    float sw = 0.f, shs = 0.f;
    #pragma unroll
    for (int j = 0; j < NBINS; j++) {
        sw += __expf(p[j] - mw);
        shs += __expf(p[NBINS + j] - mh);
    }
    const float span = 1.0f - NBINS * 1e-4f;
    float scw = span / sw, sch = span / shs;
    float cumw = 0.f, cumh = 0.f;
    float xk = 0.f, yk = 0.f, wk = 0.f, hk = 0.f;
    int k = 0;
    #pragma unroll
    for (int j = 0; j < NBINS; j++) {
        float wj = __expf(p[j] - mw) * scw + 1e-4f;
        float hj = __expf(p[NBINS + j] - mh) * sch + 1e-4f;
        if (xc >= cumw) { k = j; xk = cumw; yk = cumh; wk = wj; hk = hj; }
        cumw += wj; cumh += hj;
    }
    float offset = logf(expm1f(0.9999f));
    float t0 = p[2 * NBINS + k] + offset;
    float t1 = ((k == NBINS - 1) ? p[2 * NBINS] : p[2 * NBINS + k + 1]) + offset;
    float dk  = ((t0 > 15.f) ? t0 : log1pf(__expf(t0))) + 1e-4f;
    float dk1 = ((t1 > 15.f) ? t1 : log1pf(__expf(t1))) + 1e-4f;
    float sl = hk / wk;
    float z = (xc - xk) / wk;
    float z1 = 1.f - z;
    float den = sl + (dk1 + dk - 2.f * sl) * z * z1;
    float y = yk + hk * (sl * z * z + dk * z * z1) / den;
    float ldv = 2.f * logf(sl)
              + logf(dk1 * z * z + 2.f * sl * z * z1 + dk * z1 * z1)
              - 2.f * logf(den);
    bool inside = (x >= 0.f) && (x <= 1.f);
    *yout = inside ? y : x;
    return inside ? ldv : 0.f;
}

// ---------------------------------------------------------------------------
// Affine-tail chain (A/B test of batched-load direct-W streaming):
// hb -> aff0(relu) -> aff1(relu) -> aff2 -> spline, ONE kernel, NO barriers
// between K-chunks. Block = 8 rows x 256 threads (4 waves), grid 256.
// Per col-pass: 8 independent W-loads batched into regs (one waitcnt), then
// 8 MFMAs. VGPR-rich (~120) so loads issue concurrently — the fix for the
// round-3 serial-load failure (VALUBusy 3%). Activations ping-pong in LDS.
// ---------------------------------------------------------------------------
#define LDA 520

template<int K, int M, bool RELU>
__device__ __forceinline__ void aff_stage(
    const unsigned short (*IN)[LDA], unsigned short (*OUT)[LDA],
    const unsigned short* __restrict__ W, const float* __restrict__ bias,
    int wv, int quad, int l16)
{
    constexpr int NI = K / 32;
    bf16x8 af[NI];
    #pragma unroll
    for (int i = 0; i < NI; i++)
        af[i] = *(const bf16x8*)&IN[l16 & 7][(i << 5) + (quad << 3)];
    #pragma unroll
    for (int p = 0; p < M / 64; p++) {
        int col = (p << 6) + (wv << 4) + l16;
        const unsigned short* wp = W + (size_t)col * K + (quad << 3);
        f32x4 acc = {0.f, 0.f, 0.f, 0.f};
        #pragma unroll
        for (int kc = 0; kc < K / 256; kc++) {
            bf16x8 w[8];                         // 8 independent loads, 1 waitcnt
            #pragma unroll
            for (int j = 0; j < 8; j++)
                w[j] = *(const bf16x8*)(wp + (kc << 8) + (j << 5));
            #pragma unroll
            for (int j = 0; j < 8; j++)
                acc = __builtin_amdgcn_mfma_f32_16x16x32_bf16(
                          af[(kc << 3) + j], w[j], acc, 0, 0, 0);
        }
        if (quad < 2) {                          // rows 0..7 only
            float bv = bias[col];
            #pragma unroll
            for (int r = 0; r < 4; r++) {
                float v = acc[r] + bv;
                if (RELU) v = fmaxf(v, 0.f);
                OUT[(quad << 2) + r][col] = f2b(v);
            }
        }
    }
}

__global__ __launch_bounds__(256) void aff_chain_kernel(
    const unsigned short* __restrict__ hb,
    const unsigned short* __restrict__ wbp_aw0,
    const unsigned short* __restrict__ wbp_aw1,
    const unsigned short* __restrict__ wbp_aw2,
    const float* __restrict__ a_b0, const float* __restrict__ a_b1,
    const float* __restrict__ a_b2,
    const float* __restrict__ pos, float* __restrict__ out)
{
    __shared__ unsigned short actA[8][LDA];
    __shared__ unsigned short actB[8][LDA];
    __shared__ float pl[8][52];

    int tid = threadIdx.x;
    int wv = tid >> 6, lane = tid & 63;
    int quad = lane >> 4, l16 = lane & 15;
    int row0 = blockIdx.x << 3;                  // 8 rows/block, 256 blocks

    {   // load 8 rows x 256 cols of hb
        int r = tid >> 5, c = (tid & 31) << 3;
        *(u16x8*)&actA[r][c] = *(const u16x8*)(hb + (size_t)(row0 + r) * 256 + c);
    }
    __syncthreads();
    aff_stage<256, 512, true>(actA, actB, wbp_aw0, a_b0, wv, quad, l16);
    __syncthreads();
    aff_stage<512, 512, true>(actB, actA, wbp_aw1, a_b1, wv, quad, l16);
    __syncthreads();
    {   // aff2: K=512, M=64 single pass (cols >= 49 discarded; W row clamped)
        bf16x8 af[16];
        #pragma unroll
        for (int i = 0; i < 16; i++)
            af[i] = *(const bf16x8*)&actA[l16 & 7][(i << 5) + (quad << 3)];
        int col = (wv << 4) + l16;               // 0..63
        int wr = (col < AFF_OUT) ? col : (AFF_OUT - 1);
        const unsigned short* wp = wbp_aw2 + (size_t)wr * 512 + (quad << 3);
        f32x4 acc = {0.f, 0.f, 0.f, 0.f};
        #pragma unroll
        for (int kc = 0; kc < 2; kc++) {
            bf16x8 w[8];
            #pragma unroll
            for (int j = 0; j < 8; j++)
                w[j] = *(const bf16x8*)(wp + (kc << 8) + (j << 5));
            #pragma unroll
            for (int j = 0; j < 8; j++)
                acc = __builtin_amdgcn_mfma_f32_16x16x32_bf16(
                          af[(kc << 3) + j], w[j], acc, 0, 0, 0);
        }
        if (quad < 2 && col < AFF_OUT) {
            float bv = a_b2[col];
            #pragma unroll
            for (int r = 0; r < 4; r++)
                pl[(quad << 2) + r][col] = acc[r] + bv;
        }
    }
    __syncthreads();
    if (tid < 8) {
        float ld = 0.f;
        int grow = row0 + tid;
        if (grow < S_ROWS) {
            float x = pos[(grow + 1) * 3 + 2];
            float y;
            ld = spline_row(&pl[tid][0], x, &y);
            out[(grow + 1) * 3 + 2] = y;
        }
        #pragma unroll
        for (int st = 4; st > 0; st >>= 1) ld += __shfl_xor(ld, st, 64);
        if (tid == 0) atomicAdd(&out[6144], ld);
    }
}

// ---------------------------------------------------------------------------
extern "C" void kernel_launch(void* const* d_in, const int* in_sizes, int n_in,
                              void* d_out, int out_size, void* d_ws, size_t ws_size,
                              hipStream_t stream)
{
    const float* pos   = (const float*)d_in[0];
    const float* scale = (const float*)d_in[1];
    const float* press = (const float*)d_in[2];
    const float* temp  = (const float*)d_in[3];
    const float* e_w0  = (const float*)d_in[4];
    const float* e_b0  = (const float*)d_in[5];
    const float* e_w1  = (const float*)d_in[6];
    const float* e_b1  = (const float*)d_in[7];
    const float* e_w2  = (const float*)d_in[8];
    const float* e_b2  = (const float*)d_in[9];
    const float* Wq    = (const float*)d_in[10];
    const float* Wk    = (const float*)d_in[11];
    const float* bk    = (const float*)d_in[12];
    const float* Wv    = (const float*)d_in[13];
    const float* Wo    = (const float*)d_in[14];
    const float* bo    = (const float*)d_in[15];
    const float* mw0   = (const float*)d_in[16];
    const float* mb0   = (const float*)d_in[17];
    const float* mw1   = (const float*)d_in[18];
    const float* mb1   = (const float*)d_in[19];
    const float* mw2   = (const float*)d_in[20];
    const float* mb2   = (const float*)d_in[21];
    const float* a_w0  = (const float*)d_in[22];
    const float* a_b0  = (const float*)d_in[23];
    const float* a_w1  = (const float*)d_in[24];
    const float* a_b1  = (const float*)d_in[25];
    const float* a_w2  = (const float*)d_in[26];
    const float* a_b2  = (const float*)d_in[27];
    float* out = (float*)d_out;

    // bf16 weight region offsets (u16 elements): [ew0p | main segments]
    enum { OFF_EW0 = 0,
           OFF_EW1 = 32768 + 0,       OFF_EW2 = 32768 + 262144,
           OFF_WQ  = 32768 + 393216,  OFF_WK  = 32768 + 655360,
           OFF_WV  = 32768 + 917504,  OFF_WO  = 32768 + 1179648,
           OFF_MW0 = 32768 + 1441792, OFF_MW1 = 32768 + 1966080,
           OFF_MW2 = 32768 + 3014656, OFF_AW0 = 32768 + 3538944,
           OFF_AW1 = 32768 + 3670016, OFF_AW2 = 32768 + 3932160 };
    const size_t WB_U16 = (size_t)EW0P_N + W_MAIN;   // 3990016

    float* ws = (float*)d_ws;
    size_t off = 0;
    float* hbuf = ws + off; off += 2048 * 256;             // f32 residual stream
    unsigned short* wbp   = (unsigned short*)(ws + off); off += WB_U16 / 2;
    unsigned short* cond  = (unsigned short*)(ws + off); off += 2048 * 64 / 2;
    unsigned short* t1b   = (unsigned short*)(ws + off); off += 2048 * 512 / 2;
    unsigned short* t2b   = (unsigned short*)(ws + off); off += 2048 * 512 / 2;
    unsigned short* hb    = (unsigned short*)(ws + off); off += 2048 * 256 / 2;
    unsigned short* obb   = (unsigned short*)(ws + off); off += 2048 * 256 / 2;
    unsigned short* qbh   = (unsigned short*)(ws + off); off += NHEADS * 2048 * 32 / 2;
    unsigned short* kbh   = (unsigned short*)(ws + off); off += NHEADS * 2048 * 32 / 2;
    unsigned short* vbT   = (unsigned short*)(ws + off); off += NHEADS * 2048 * 32 / 2;
    (void)ws_size;

    hipLaunchKernelGGL(setup_kernel, dim3(1024), dim3(256), 0, stream,
                       pos, scale, press, temp, e_w0,
                       e_w1, e_w2, Wq, Wk, Wv, Wo, mw0, mw1, mw2,
                       a_w0, a_w1, a_w2, wbp, cond, out);

    auto gemm = [&](const unsigned short* A, const unsigned short* W,
                    const float* bias, const float* resF, float* Cf,
                    unsigned short* Cb, int M, int K, int relu) {
        dim3 grid((M + 31) / 32, 64);
        if (K % 128 == 0)
            hipLaunchKernelGGL(gemm_bf16_128, grid, dim3(256), 0, stream,
                               A, W, bias, resF, Cf, Cb, M, K, relu);
        else
            hipLaunchKernelGGL(gemm_bf16_64, grid, dim3(256), 0, stream,
                               A, W, bias, resF, Cf, Cb, M, K, relu);
    };

    // embedding MLP: 35(->64) -> 512 -> 512 -> 256
    gemm(cond, wbp + OFF_EW0, e_b0, nullptr, nullptr, t1b, 512, 64, 1);
    gemm(t1b,  wbp + OFF_EW1, e_b1, nullptr, nullptr, t2b, 512, 512, 1);
    gemm(t2b,  wbp + OFF_EW2, e_b2, nullptr, hbuf, hb, 256, 512, 0);

    for (int l = 0; l < 4; l++) {
        hipLaunchKernelGGL(gemm_qkv, dim3(24, 64), dim3(256), 0, stream,
                           hb, wbp + OFF_WQ + l * 65536, wbp + OFF_WK + l * 65536,
                           wbp + OFF_WV + l * 65536, bk + l * 256, qbh, kbh, vbT);
        hipLaunchKernelGGL(attn_mfma, dim3(64, NHEADS), dim3(512), 0, stream,
                           qbh, kbh, vbT, obb);
        gemm(obb, wbp + OFF_WO + l * 65536, bo + l * 256, hbuf, hbuf, hb, 256, 256, 0);
        gemm(hb,  wbp + OFF_MW0 + l * 131072, mb0 + l * 512, nullptr, nullptr, t1b, 512, 256, 1);
        gemm(t1b, wbp + OFF_MW1 + l * 262144, mb1 + l * 512, nullptr, nullptr, t2b, 512, 512, 1);
        gemm(t2b, wbp + OFF_MW2 + l * 131072, mb2 + l * 256, hbuf, hbuf, hb, 256, 512, 0);
    }

    // affine-param tail: ONE fused chain kernel (aff0 + aff1 + aff2 + spline)
    hipLaunchKernelGGL(aff_chain_kernel, dim3(256), dim3(256), 0, stream,
                       hb, wbp + OFF_AW0, wbp + OFF_AW1, wbp + OFF_AW2,
                       a_b0, a_b1, a_b2, pos, out);
}

// Round 9
// 336.985 us; speedup vs baseline: 1.0488x; 1.0488x over previous
//
#include <hip/hip_runtime.h>
#include <math.h>

#define S_ROWS 2047
#define DIM 256
#define HID 512
#define NHEADS 8
#define DH 32
#define NBINS 16
#define AFF_OUT 49

typedef short bf16x8 __attribute__((ext_vector_type(8)));
typedef float f32x4 __attribute__((ext_vector_type(4)));
typedef float f32x16 __attribute__((ext_vector_type(16)));
typedef unsigned short u16x8 __attribute__((ext_vector_type(8)));
typedef unsigned short u16x4 __attribute__((ext_vector_type(4)));

__device__ inline unsigned short f2b(float f) {
    unsigned int u = __float_as_uint(f);
    u += 0x7FFFu + ((u >> 16) & 1u);      // round-to-nearest-even
    return (unsigned short)(u >> 16);
}

// ---------------------------------------------------------------------------
// Fused setup (verified): weight f32->bf16 conversion (+ew0 zero-pad to K=64),
// circular-feature embedding, pos copy + out[6144]=0.
// ---------------------------------------------------------------------------
#define W_MAIN 3957248
#define EW0P_N 32768
#define P0 (W_MAIN / 4)
#define P1 (P0 + EW0P_N / 4)
#define P2 (P1 + 2048 * 64 / 4)
#define P3 (P2 + 1537)
__global__ __launch_bounds__(256) void setup_kernel(
    const float* __restrict__ pos, const float* __restrict__ scale,
    const float* __restrict__ press, const float* __restrict__ temp,
    const float* __restrict__ e_w0, const float* __restrict__ p0,
    const float* __restrict__ p1, const float* __restrict__ p2,
    const float* __restrict__ p3, const float* __restrict__ p4,
    const float* __restrict__ p5, const float* __restrict__ p6,
    const float* __restrict__ p7, const float* __restrict__ p8,
    const float* __restrict__ p9, const float* __restrict__ p10,
    const float* __restrict__ p11, unsigned short* __restrict__ dst,
    unsigned short* __restrict__ cond, float* __restrict__ out)
{
    const int offs[13] = {0, 262144, 393216, 655360, 917504, 1179648, 1441792,
                          1966080, 3014656, 3538944, 3670016, 3932160, 3957248};
    const float* srcs[12] = {p0,p1,p2,p3,p4,p5,p6,p7,p8,p9,p10,p11};
    for (int i4 = blockIdx.x * blockDim.x + threadIdx.x; i4 < P3;
         i4 += gridDim.x * blockDim.x) {
        if (i4 < P0) {
            int e = i4 * 4;
            int s = 0;
            #pragma unroll
            for (int j = 1; j < 12; j++) s += (e >= offs[j]);
            const float4 v = *(const float4*)(srcs[s] + (e - offs[s]));
            u16x4 o;
            o[0] = f2b(v.x); o[1] = f2b(v.y); o[2] = f2b(v.z); o[3] = f2b(v.w);
            *(u16x4*)(dst + EW0P_N + e) = o;
        } else if (i4 < P1) {
            int e = (i4 - P0) * 4;
            u16x4 o;
            #pragma unroll
            for (int r = 0; r < 4; r++) {
                int ee = e + r;
                int row = ee >> 6, col = ee & 63;
                o[r] = (col < 35) ? f2b(e_w0[row * 35 + col]) : (unsigned short)0;
            }
            *(u16x4*)(dst + e) = o;
        } else if (i4 < P2) {
            int e = (i4 - P1) * 4;
            int row = e >> 6;
            u16x4 o;
            #pragma unroll
            for (int r = 0; r < 4; r++) {
                int c = (e + r) & 63;
                float v = 0.f;
                if (row < S_ROWS) {
                    if (c < 32) {
                        int coord = c >> 4;
                        int w = c & 15;
                        float x = pos[(row + 1) * 3 + coord];
                        float f = 6.283185307179586f * (float)((w & 7) + 1);
                        float ang = x * f;
                        v = (w < 8) ? cosf(ang) : sinf(ang);
                    } else if (c == 32) v = scale[0];
                    else if (c == 33) v = temp[0];
                    else if (c == 34) v = press[0];
                }
                o[r] = f2b(v);
            }
            *(u16x4*)(cond + e) = o;
        } else {
            int e = (i4 - P2) * 4;
            #pragma unroll
            for (int r = 0; r < 4; r++) {
                int ee = e + r;
                if (ee < 6144) out[ee] = pos[ee];
                else if (ee == 6144) out[ee] = 0.f;
            }
        }
    }
}

// ---------------------------------------------------------------------------
// bf16 MFMA GEMM, 32x32 tile, KSTEP=64 (verified; used for K=64 only).
// ---------------------------------------------------------------------------
#define LDK 72
__global__ __launch_bounds__(256, 4) void gemm_bf16_64(
    const unsigned short* __restrict__ Ab, const unsigned short* __restrict__ W,
    const float* __restrict__ bias, const float* resF,
    float* Cf, unsigned short* Cb, int M, int K, int relu)
{
    __shared__ unsigned short As[32][LDK];
    __shared__ unsigned short Bs[32][LDK];
    int tid = threadIdx.x;
    int wave = tid >> 6, lane = tid & 63;
    int quad = lane >> 4, l16 = lane & 15;
    int rowf = (wave & 1) << 4, colf = (wave >> 1) << 4;
    int row0 = blockIdx.y << 5, col0 = blockIdx.x << 5;
    int srow = tid >> 3, scol = (tid & 7) << 3;

    f32x4 acc = {0.f, 0.f, 0.f, 0.f};

    const u16x8* ap = (const u16x8*)(Ab + (size_t)(row0 + srow) * K + scol);
    const u16x8* wp = (const u16x8*)(W + (size_t)(col0 + srow) * K + scol);
    u16x8 a0 = ap[0];
    u16x8 b0 = wp[0];

    for (int k0 = 0; k0 < K; k0 += 64) {
        *(u16x8*)&As[srow][scol] = a0;
        *(u16x8*)&Bs[srow][scol] = b0;
        __syncthreads();
        if (k0 + 64 < K) {
            ap += 8; wp += 8;
            a0 = ap[0]; b0 = wp[0];
        }
        #pragma unroll
        for (int kt = 0; kt < 64; kt += 32) {
            bf16x8 af = *(bf16x8*)&As[rowf + l16][kt + (quad << 3)];
            bf16x8 bf = *(bf16x8*)&Bs[colf + l16][kt + (quad << 3)];
            acc = __builtin_amdgcn_mfma_f32_16x16x32_bf16(af, bf, acc, 0, 0, 0);
        }
        __syncthreads();
    }
    int col = col0 + colf + l16;
    if (col < M) {
        float bv = bias ? bias[col] : 0.f;
        #pragma unroll
        for (int r = 0; r < 4; r++) {
            int row = row0 + rowf + (quad << 2) + r;
            if (row >= S_ROWS) continue;
            float v = acc[r] + bv;
            if (resF) v += resF[(size_t)row * M + col];
            if (relu) v = fmaxf(v, 0.f);
            if (Cf) Cf[(size_t)row * M + col] = v;
            if (Cb) Cb[(size_t)row * M + col] = f2b(v);
        }
    }
}

// ---------------------------------------------------------------------------
// bf16 MFMA GEMM, 32x32 tile, KSTEP=128 (verified round 7). K % 128 == 0.
// ---------------------------------------------------------------------------
#define LDW 136
__global__ __launch_bounds__(256, 4) void gemm_bf16_128(
    const unsigned short* __restrict__ Ab, const unsigned short* __restrict__ W,
    const float* __restrict__ bias, const float* resF,
    float* Cf, unsigned short* Cb, int M, int K, int relu)
{
    __shared__ unsigned short As[32][LDW];
    __shared__ unsigned short Bs[32][LDW];
    int tid = threadIdx.x;
    int wave = tid >> 6, lane = tid & 63;
    int quad = lane >> 4, l16 = lane & 15;
    int rowf = (wave & 1) << 4, colf = (wave >> 1) << 4;
    int row0 = blockIdx.y << 5, col0 = blockIdx.x << 5;
    int srow = tid >> 3, scol = (tid & 7) << 4;

    f32x4 acc = {0.f, 0.f, 0.f, 0.f};

    const u16x8* ap = (const u16x8*)(Ab + (size_t)(row0 + srow) * K + scol);
    const u16x8* wp = (const u16x8*)(W + (size_t)(col0 + srow) * K + scol);
    u16x8 a0 = ap[0], a1 = ap[1];
    u16x8 b0 = wp[0], b1 = wp[1];

    for (int k0 = 0; k0 < K; k0 += 128) {
        *(u16x8*)&As[srow][scol]     = a0;
        *(u16x8*)&As[srow][scol + 8] = a1;
        *(u16x8*)&Bs[srow][scol]     = b0;
        *(u16x8*)&Bs[srow][scol + 8] = b1;
        __syncthreads();
        if (k0 + 128 < K) {
            ap += 16; wp += 16;
            a0 = ap[0]; a1 = ap[1];
            b0 = wp[0]; b1 = wp[1];
        }
        #pragma unroll
        for (int kt = 0; kt < 128; kt += 32) {
            bf16x8 af = *(bf16x8*)&As[rowf + l16][kt + (quad << 3)];
            bf16x8 bf = *(bf16x8*)&Bs[colf + l16][kt + (quad << 3)];
            acc = __builtin_amdgcn_mfma_f32_16x16x32_bf16(af, bf, acc, 0, 0, 0);
        }
        __syncthreads();
    }
    int col = col0 + colf + l16;
    if (col < M) {
        float bv = bias ? bias[col] : 0.f;
        #pragma unroll
        for (int r = 0; r < 4; r++) {
            int row = row0 + rowf + (quad << 2) + r;
            if (row >= S_ROWS) continue;
            float v = acc[r] + bv;
            if (resF) v += resF[(size_t)row * M + col];
            if (relu) v = fmaxf(v, 0.f);
            if (Cf) Cf[(size_t)row * M + col] = v;
            if (Cb) Cb[(size_t)row * M + col] = f2b(v);
        }
    }
}

// ---------------------------------------------------------------------------
// Fused QKV GEMM (32x32 tile, KSTEP=128, K=256) -> attention-native layouts
// (verified). Grid (24, 64) = 1536 blocks.
// ---------------------------------------------------------------------------
__global__ __launch_bounds__(256, 4) void gemm_qkv(
    const unsigned short* __restrict__ Ab, const unsigned short* __restrict__ Wq,
    const unsigned short* __restrict__ Wk, const unsigned short* __restrict__ Wv,
    const float* __restrict__ bk,
    unsigned short* __restrict__ qbh, unsigned short* __restrict__ kbh,
    unsigned short* __restrict__ vbT)
{
    __shared__ unsigned short As[32][LDW];
    __shared__ unsigned short Bs[32][LDW];
    const int N = S_ROWS, K = 256;
    int tid = threadIdx.x;
    int wave = tid >> 6, lane = tid & 63;
    int quad = lane >> 4, l16 = lane & 15;
    int rowf = (wave & 1) << 4, colf = (wave >> 1) << 4;
    int row0 = blockIdx.y << 5, col0 = blockIdx.x << 5;
    int mode = col0 >> 8;                 // 0=q 1=k 2=v
    int wcol0 = col0 & 255;
    const unsigned short* W = (mode == 0) ? Wq : (mode == 1) ? Wk : Wv;
    int srow = tid >> 3, scol = (tid & 7) << 4;

    f32x4 acc = {0.f, 0.f, 0.f, 0.f};

    const u16x8* ap = (const u16x8*)(Ab + (size_t)(row0 + srow) * K + scol);
    const u16x8* wp = (const u16x8*)(W + (size_t)(wcol0 + srow) * K + scol);
    u16x8 a0 = ap[0], a1 = ap[1];
    u16x8 b0 = wp[0], b1 = wp[1];

    for (int k0 = 0; k0 < K; k0 += 128) {
        *(u16x8*)&As[srow][scol]     = a0;
        *(u16x8*)&As[srow][scol + 8] = a1;
        *(u16x8*)&Bs[srow][scol]     = b0;
        *(u16x8*)&Bs[srow][scol + 8] = b1;
        __syncthreads();
        if (k0 + 128 < K) {
            ap += 16; wp += 16;
            a0 = ap[0]; a1 = ap[1];
            b0 = wp[0]; b1 = wp[1];
        }
        #pragma unroll
        for (int kt = 0; kt < 128; kt += 32) {
            bf16x8 af = *(bf16x8*)&As[rowf + l16][kt + (quad << 3)];
            bf16x8 bf = *(bf16x8*)&Bs[colf + l16][kt + (quad << 3)];
            acc = __builtin_amdgcn_mfma_f32_16x16x32_bf16(af, bf, acc, 0, 0, 0);
        }
        __syncthreads();
    }
    int colr = wcol0 + colf + l16;        // 0..255
    int hh = colr >> 5, d = colr & 31;
    int rbase = row0 + rowf + (quad << 2);
    if (mode == 2) {
        unsigned short* dst = vbT + ((size_t)hh * 32 + d) * 2048 + rbase;
        if (rbase + 3 < N) {
            u16x4 o;
            #pragma unroll
            for (int r = 0; r < 4; r++) o[r] = f2b(acc[r]);
            *(u16x4*)dst = o;
        } else {
            #pragma unroll
            for (int r = 0; r < 4; r++)
                if (rbase + r < N) dst[r] = f2b(acc[r]);
        }
    } else {
        float bias = (mode == 1) ? bk[colr] : 0.f;
        unsigned short* dst = ((mode == 0) ? qbh : kbh) + (size_t)hh * 2048 * 32 + d;
        #pragma unroll
        for (int r = 0; r < 4; r++) {
            int row = rbase + r;
            if (row < N) {
                float v = acc[r] + bias;
                if (mode == 0) v *= 0.25506362f;
                dst[(size_t)row * 32] = f2b(v);
            }
        }
    }
}

// ---------------------------------------------------------------------------
// MFMA flash attention, 8-wave split-K-8 (verified round 7).
// Grid (64, 8) = 512 blocks x 512 threads.
// ---------------------------------------------------------------------------
__global__ __launch_bounds__(512, 2) void attn_mfma(
    const unsigned short* __restrict__ qbh,
    const unsigned short* __restrict__ kbh,
    const unsigned short* __restrict__ vbT,
    unsigned short* __restrict__ obb)
{
    int tid = threadIdx.x;
    int w = tid >> 6;                     // wave = K-chunk (0..7)
    int lane = tid & 63;
    int l31 = lane & 31, hf = lane >> 5;
    int q0 = blockIdx.x << 5;
    int h = blockIdx.y;
    int kstart = w * 256;
    int kend = min(kstart + 256, S_ROWS);

    const unsigned short* qp = qbh + ((size_t)h * 2048 + (q0 + l31)) * 32 + hf * 8;
    bf16x8 qf0 = *(const bf16x8*)(qp);
    bf16x8 qf1 = *(const bf16x8*)(qp + 16);

    const unsigned short* kb_h = kbh + (size_t)h * 2048 * 32;
    const unsigned short* vb_h = vbT + ((size_t)h * 32 + l31) * 2048;

    f32x16 acc = {};
    float m = -1e30f, l = 0.f;

    for (int key0 = kstart; key0 < kend; key0 += 32) {
        const unsigned short* kp = kb_h + (size_t)(key0 + l31) * 32 + hf * 8;
        bf16x8 kf0 = *(const bf16x8*)(kp);
        bf16x8 kf1 = *(const bf16x8*)(kp + 16);
        bf16x8 vf0 = *(const bf16x8*)(vb_h + key0 + hf * 8);
        bf16x8 vf1 = *(const bf16x8*)(vb_h + key0 + 16 + hf * 8);

        f32x16 sc = {};
        sc = __builtin_amdgcn_mfma_f32_32x32x16_bf16(kf0, qf0, sc, 0, 0, 0);
        sc = __builtin_amdgcn_mfma_f32_32x32x16_bf16(kf1, qf1, sc, 0, 0, 0);

        if (key0 + 32 > kend) {
            #pragma unroll
            for (int r = 0; r < 16; r++) {
                int kr = key0 + (r & 3) + 8 * (r >> 2) + 4 * hf;
                if (kr >= kend) sc[r] = -1e30f;
            }
        }
        float tmax = sc[0];
        #pragma unroll
        for (int r = 1; r < 16; r++) tmax = fmaxf(tmax, sc[r]);
        tmax = fmaxf(tmax, __shfl_xor(tmax, 32, 64));
        float mnew = fmaxf(m, tmax);
        float corr = __builtin_amdgcn_exp2f(m - mnew);
        m = mnew;
        float p[16];
        float ls = 0.f;
        #pragma unroll
        for (int r = 0; r < 16; r++) {
            p[r] = __builtin_amdgcn_exp2f(sc[r] - mnew);
            ls += p[r];
        }
        ls += __shfl_xor(ls, 32, 64);
        l = l * corr + ls;
        if (__ballot(corr != 1.0f)) {
            #pragma unroll
            for (int r = 0; r < 16; r++) acc[r] *= corr;
        }
        unsigned int pk[8];
        #pragma unroll
        for (int i = 0; i < 8; i++)
            pk[i] = __builtin_amdgcn_perm(__float_as_uint(p[2*i+1]),
                                          __float_as_uint(p[2*i]), 0x07060302u);
        unsigned int x[8];
        #pragma unroll
        for (int i = 0; i < 8; i++)
            x[i] = (unsigned int)__shfl_xor((int)pk[i], 32, 64);
        union { unsigned int u[4]; bf16x8 v; } B1, B2;
        B1.u[0] = hf ? x[2]  : pk[0];
        B1.u[1] = hf ? x[3]  : pk[1];
        B1.u[2] = hf ? pk[2] : x[0];
        B1.u[3] = hf ? pk[3] : x[1];
        B2.u[0] = hf ? x[6]  : pk[4];
        B2.u[1] = hf ? x[7]  : pk[5];
        B2.u[2] = hf ? pk[6] : x[4];
        B2.u[3] = hf ? pk[7] : x[5];
        acc = __builtin_amdgcn_mfma_f32_32x32x16_bf16(vf0, B1.v, acc, 0, 0, 0);
        acc = __builtin_amdgcn_mfma_f32_32x32x16_bf16(vf1, B2.v, acc, 0, 0, 0);
    }

    // ---- in-block split-K-8 combine through LDS ----
    __shared__ float sm_m[8][32];
    __shared__ float sm_l[8][32];
    __shared__ float sm_acc[8][32][36];
    if (!hf) { sm_m[w][l31] = m; sm_l[w][l31] = l; }
    #pragma unroll
    for (int g = 0; g < 4; g++) {
        float4 o4;
        o4.x = acc[4*g]; o4.y = acc[4*g+1]; o4.z = acc[4*g+2]; o4.w = acc[4*g+3];
        *(float4*)&sm_acc[w][l31][8*g + 4*hf] = o4;
    }
    __syncthreads();

    if (tid < 256) {
        int q = tid & 31;
        int dg = tid >> 5;                // 0..7
        float mmax = -1e30f;
        #pragma unroll
        for (int c = 0; c < 8; c++) mmax = fmaxf(mmax, sm_m[c][q]);
        float lsum = 0.f;
        float num0 = 0.f, num1 = 0.f, num2 = 0.f, num3 = 0.f;
        #pragma unroll
        for (int c = 0; c < 8; c++) {
            float wgt = __builtin_amdgcn_exp2f(sm_m[c][q] - mmax);
            lsum += sm_l[c][q] * wgt;
            float4 o4 = *(const float4*)&sm_acc[c][q][dg * 4];
            num0 = fmaf(o4.x, wgt, num0);
            num1 = fmaf(o4.y, wgt, num1);
            num2 = fmaf(o4.z, wgt, num2);
            num3 = fmaf(o4.w, wgt, num3);
        }
        float inv = 1.f / lsum;
        if (q0 + q < S_ROWS) {
            u16x4 st;
            st[0] = f2b(num0 * inv); st[1] = f2b(num1 * inv);
            st[2] = f2b(num2 * inv); st[3] = f2b(num3 * inv);
            *(u16x4*)(obb + (size_t)(q0 + q) * DIM + h * DH + dg * 4) = st;
        }
    }
}

// ---------------------------------------------------------------------------
// RQS spline for one row (verified math).
// ---------------------------------------------------------------------------
__device__ __forceinline__ float spline_row(const float* p, float x, float* yout)
{
    float xc = fminf(fmaxf(x, 0.f), 1.f);
    float mw = -1e30f, mh = -1e30f;
    #pragma unroll
    for (int j = 0; j < NBINS; j++) {
        mw = fmaxf(mw, p[j]);
        mh = fmaxf(mh, p[NBINS + j]);
    }
    float sw = 0.f, shs = 0.f;
    #pragma unroll
    for (int j = 0; j < NBINS; j++) {
        sw += __expf(p[j] - mw);
        shs += __expf(p[NBINS + j] - mh);
    }
    const float span = 1.0f - NBINS * 1e-4f;
    float scw = span / sw, sch = span / shs;
    float cumw = 0.f, cumh = 0.f;
    float xk = 0.f, yk = 0.f, wk = 0.f, hk = 0.f;
    int k = 0;
    #pragma unroll
    for (int j = 0; j < NBINS; j++) {
        float wj = __expf(p[j] - mw) * scw + 1e-4f;
        float hj = __expf(p[NBINS + j] - mh) * sch + 1e-4f;
        if (xc >= cumw) { k = j; xk = cumw; yk = cumh; wk = wj; hk = hj; }
        cumw += wj; cumh += hj;
    }
    float offset = logf(expm1f(0.9999f));
    float t0 = p[2 * NBINS + k] + offset;
    float t1 = ((k == NBINS - 1) ? p[2 * NBINS] : p[2 * NBINS + k + 1]) + offset;
    float dk  = ((t0 > 15.f) ? t0 : log1pf(__expf(t0))) + 1e-4f;
    float dk1 = ((t1 > 15.f) ? t1 : log1pf(__expf(t1))) + 1e-4f;
    float sl = hk / wk;
    float z = (xc - xk) / wk;
    float z1 = 1.f - z;
    float den = sl + (dk1 + dk - 2.f * sl) * z * z1;
    float y = yk + hk * (sl * z * z + dk * z * z1) / den;
    float ldv = 2.f * logf(sl)
              + logf(dk1 * z * z + 2.f * sl * z * z1 + dk * z1 * z1)
              - 2.f * logf(den);
    bool inside = (x >= 0.f) && (x <= 1.f);
    *yout = inside ? y : x;
    return inside ? ldv : 0.f;
}

// ---------------------------------------------------------------------------
// Fused aff2 GEMM + spline. Block = 32 rows x ALL 64 output cols (M=49 valid)
// -> each block holds its rows' complete spline params in LDS; spline runs
// in-kernel. Verified KSTEP=128 stage/prefetch GEMM structure, K=512.
// Grid 64 x 256 threads. Replaces 2 dispatches (aff2 gemm + spline kernel).
// ---------------------------------------------------------------------------
__global__ __launch_bounds__(256, 2) void aff_tail_kernel(
    const unsigned short* __restrict__ Ab,     // t2b [2048][512]
    const unsigned short* __restrict__ W2,     // AW2 [49][512]
    const float* __restrict__ a_b2,
    const float* __restrict__ pos, float* __restrict__ out)
{
    __shared__ unsigned short As[32][LDW];
    __shared__ unsigned short Bs[64][LDW];
    __shared__ float pl[32][52];
    const int K = 512;

    int tid = threadIdx.x;
    int wave = tid >> 6, lane = tid & 63;
    int quad = lane >> 4, l16 = lane & 15;
    int rowf = (wave & 1) << 4, colf = (wave >> 1) << 4;
    int row0 = blockIdx.x << 5;                  // 32 rows/block, 64 blocks

    int srow = tid >> 3, scol = (tid & 7) << 4;  // A stage: 32 rows x 128 k
    int wrB = tid >> 2, kbB = (tid & 3) << 5;    // B stage: 64 rows x 128 k
    int wr = (wrB < AFF_OUT) ? wrB : (AFF_OUT - 1);  // clamp W row (rows 49..63 dup)

    f32x4 acc[2];
    acc[0] = f32x4{0.f, 0.f, 0.f, 0.f};
    acc[1] = f32x4{0.f, 0.f, 0.f, 0.f};

    const u16x8* ap = (const u16x8*)(Ab + (size_t)(row0 + srow) * K + scol);
    const u16x8* wp = (const u16x8*)(W2 + (size_t)wr * K + kbB);
    u16x8 a0 = ap[0], a1 = ap[1];
    u16x8 b0 = wp[0], b1 = wp[1], b2 = wp[2], b3 = wp[3];

    for (int k0 = 0; k0 < K; k0 += 128) {
        *(u16x8*)&As[srow][scol]      = a0;
        *(u16x8*)&As[srow][scol + 8]  = a1;
        *(u16x8*)&Bs[wrB][kbB]        = b0;
        *(u16x8*)&Bs[wrB][kbB + 8]    = b1;
        *(u16x8*)&Bs[wrB][kbB + 16]   = b2;
        *(u16x8*)&Bs[wrB][kbB + 24]   = b3;
        __syncthreads();
        if (k0 + 128 < K) {              // prefetch next tile (stays in flight)
            ap += 16; wp += 16;
            a0 = ap[0]; a1 = ap[1];
            b0 = wp[0]; b1 = wp[1]; b2 = wp[2]; b3 = wp[3];
        }
        #pragma unroll
        for (int kt = 0; kt < 128; kt += 32) {
            bf16x8 af = *(bf16x8*)&As[rowf + l16][kt + (quad << 3)];
            #pragma unroll
            for (int ct = 0; ct < 2; ct++) {
                bf16x8 bf = *(bf16x8*)&Bs[(ct << 5) + colf + l16][kt + (quad << 3)];
                acc[ct] = __builtin_amdgcn_mfma_f32_16x16x32_bf16(af, bf, acc[ct], 0, 0, 0);
            }
        }
        __syncthreads();
    }
    #pragma unroll
    for (int ct = 0; ct < 2; ct++) {
        int col = (ct << 5) + colf + l16;        // 0..63
        if (col < AFF_OUT) {
            float bv = a_b2[col];
            #pragma unroll
            for (int r = 0; r < 4; r++)
                pl[rowf + (quad << 2) + r][col] = acc[ct][r] + bv;
        }
    }
    __syncthreads();
    if (tid < 32) {
        float ld = 0.f;
        int grow = row0 + tid;
        if (grow < S_ROWS) {
            float x = pos[(grow + 1) * 3 + 2];
            float y;
            ld = spline_row(&pl[tid][0], x, &y);
            out[(grow + 1) * 3 + 2] = y;
        }
        #pragma unroll
        for (int st = 16; st > 0; st >>= 1) ld += __shfl_xor(ld, st, 64);
        if (tid == 0) atomicAdd(&out[6144], ld);
    }
}

// ---------------------------------------------------------------------------
extern "C" void kernel_launch(void* const* d_in, const int* in_sizes, int n_in,
                              void* d_out, int out_size, void* d_ws, size_t ws_size,
                              hipStream_t stream)
{
    const float* pos   = (const float*)d_in[0];
    const float* scale = (const float*)d_in[1];
    const float* press = (const float*)d_in[2];
    const float* temp  = (const float*)d_in[3];
    const float* e_w0  = (const float*)d_in[4];
    const float* e_b0  = (const float*)d_in[5];
    const float* e_w1  = (const float*)d_in[6];
    const float* e_b1  = (const float*)d_in[7];
    const float* e_w2  = (const float*)d_in[8];
    const float* e_b2  = (const float*)d_in[9];
    const float* Wq    = (const float*)d_in[10];
    const float* Wk    = (const float*)d_in[11];
    const float* bk    = (const float*)d_in[12];
    const float* Wv    = (const float*)d_in[13];
    const float* Wo    = (const float*)d_in[14];
    const float* bo    = (const float*)d_in[15];
    const float* mw0   = (const float*)d_in[16];
    const float* mb0   = (const float*)d_in[17];
    const float* mw1   = (const float*)d_in[18];
    const float* mb1   = (const float*)d_in[19];
    const float* mw2   = (const float*)d_in[20];
    const float* mb2   = (const float*)d_in[21];
    const float* a_w0  = (const float*)d_in[22];
    const float* a_b0  = (const float*)d_in[23];
    const float* a_w1  = (const float*)d_in[24];
    const float* a_b1  = (const float*)d_in[25];
    const float* a_w2  = (const float*)d_in[26];
    const float* a_b2  = (const float*)d_in[27];
    float* out = (float*)d_out;

    // bf16 weight region offsets (u16 elements): [ew0p | main segments]
    enum { OFF_EW0 = 0,
           OFF_EW1 = 32768 + 0,       OFF_EW2 = 32768 + 262144,
           OFF_WQ  = 32768 + 393216,  OFF_WK  = 32768 + 655360,
           OFF_WV  = 32768 + 917504,  OFF_WO  = 32768 + 1179648,
           OFF_MW0 = 32768 + 1441792, OFF_MW1 = 32768 + 1966080,
           OFF_MW2 = 32768 + 3014656, OFF_AW0 = 32768 + 3538944,
           OFF_AW1 = 32768 + 3670016, OFF_AW2 = 32768 + 3932160 };
    const size_t WB_U16 = (size_t)EW0P_N + W_MAIN;   // 3990016

    float* ws = (float*)d_ws;
    size_t off = 0;
    float* hbuf = ws + off; off += 2048 * 256;             // f32 residual stream
    unsigned short* wbp   = (unsigned short*)(ws + off); off += WB_U16 / 2;
    unsigned short* cond  = (unsigned short*)(ws + off); off += 2048 * 64 / 2;
    unsigned short* t1b   = (unsigned short*)(ws + off); off += 2048 * 512 / 2;
    unsigned short* t2b   = (unsigned short*)(ws + off); off += 2048 * 512 / 2;
    unsigned short* hb    = (unsigned short*)(ws + off); off += 2048 * 256 / 2;
    unsigned short* obb   = (unsigned short*)(ws + off); off += 2048 * 256 / 2;
    unsigned short* qbh   = (unsigned short*)(ws + off); off += NHEADS * 2048 * 32 / 2;
    unsigned short* kbh   = (unsigned short*)(ws + off); off += NHEADS * 2048 * 32 / 2;
    unsigned short* vbT   = (unsigned short*)(ws + off); off += NHEADS * 2048 * 32 / 2;
    (void)ws_size;

    hipLaunchKernelGGL(setup_kernel, dim3(1024), dim3(256), 0, stream,
                       pos, scale, press, temp, e_w0,
                       e_w1, e_w2, Wq, Wk, Wv, Wo, mw0, mw1, mw2,
                       a_w0, a_w1, a_w2, wbp, cond, out);

    auto gemm = [&](const unsigned short* A, const unsigned short* W,
                    const float* bias, const float* resF, float* Cf,
                    unsigned short* Cb, int M, int K, int relu) {
        dim3 grid((M + 31) / 32, 64);
        if (K % 128 == 0)
            hipLaunchKernelGGL(gemm_bf16_128, grid, dim3(256), 0, stream,
                               A, W, bias, resF, Cf, Cb, M, K, relu);
        else
            hipLaunchKernelGGL(gemm_bf16_64, grid, dim3(256), 0, stream,
                               A, W, bias, resF, Cf, Cb, M, K, relu);
    };

    // embedding MLP: 35(->64) -> 512 -> 512 -> 256
    gemm(cond, wbp + OFF_EW0, e_b0, nullptr, nullptr, t1b, 512, 64, 1);
    gemm(t1b,  wbp + OFF_EW1, e_b1, nullptr, nullptr, t2b, 512, 512, 1);
    gemm(t2b,  wbp + OFF_EW2, e_b2, nullptr, hbuf, hb, 256, 512, 0);

    for (int l = 0; l < 4; l++) {
        hipLaunchKernelGGL(gemm_qkv, dim3(24, 64), dim3(256), 0, stream,
                           hb, wbp + OFF_WQ + l * 65536, wbp + OFF_WK + l * 65536,
                           wbp + OFF_WV + l * 65536, bk + l * 256, qbh, kbh, vbT);
        hipLaunchKernelGGL(attn_mfma, dim3(64, NHEADS), dim3(512), 0, stream,
                           qbh, kbh, vbT, obb);
        gemm(obb, wbp + OFF_WO + l * 65536, bo + l * 256, hbuf, hbuf, hb, 256, 256, 0);
        gemm(hb,  wbp + OFF_MW0 + l * 131072, mb0 + l * 512, nullptr, nullptr, t1b, 512, 256, 1);
        gemm(t1b, wbp + OFF_MW1 + l * 262144, mb1 + l * 512, nullptr, nullptr, t2b, 512, 512, 1);
        gemm(t2b, wbp + OFF_MW2 + l * 131072, mb2 + l * 256, hbuf, hbuf, hb, 256, 512, 0);
    }

    // affine-param MLP: 256 -> 512 -> 512 -> (49 + spline, fused)
    gemm(hb,  wbp + OFF_AW0, a_b0, nullptr, nullptr, t1b, 512, 256, 1);
    gemm(t1b, wbp + OFF_AW1, a_b1, nullptr, nullptr, t2b, 512, 512, 1);
    hipLaunchKernelGGL(aff_tail_kernel, dim3(64), dim3(256), 0, stream,
                       t2b, wbp + OFF_AW2, a_b2, pos, out);
}